// Round 2
// baseline (538.789 us; speedup 1.0000x reference)
//
#include <hip/hip_runtime.h>
#include <hip/hip_bf16.h>

typedef __hip_bfloat16 bf16;

#define HWP 3136
#define WD 56
#define CC 128
#define MIDM 32
#define OGN 512
#define NB 4

// workspace offsets in FLOAT units. bf16 regions noted; sizes counted in floats.
enum : int {
  OFF_WKT  = 0,                        // fp32 [c][d] 128x128
  OFF_W1AT = OFF_WKT  + CC*CC,         // fp32 [c][m] 128x32
  OFF_W1BT = OFF_W1AT + CC*MIDM,       // fp32 [c][m] 128x32
  OFF_WVT  = OFF_W1BT + CC*MIDM,       // fp32 [c][o] 128x512
  OFF_SC1  = OFF_WVT  + CC*OGN,        // [128]
  OFF_SH1  = OFF_SC1  + CC,            // [128]
  OFF_SC2  = OFF_SH1  + CC,            // [32]
  OFF_SH2  = OFF_SC2  + MIDM,          // [32]
  OFF_B1F  = OFF_SH2  + MIDM,          // [32]
  OFF_SCV  = OFF_B1F  + MIDM,          // [512]
  OFF_SHV  = OFF_SCV  + OGN,           // [512]
  OFF_W2F  = OFF_SHV  + OGN,           // fp32 [o][m] 512x32
  OFF_B2F  = OFF_W2F  + OGN*MIDM,      // [512]
  OFF_GNG  = OFF_B2F  + OGN,           // [512]
  OFF_GNB  = OFF_GNG  + OGN,           // [512]
  OFF_FLAG = OFF_GNB  + OGN,           // [4]  flag[0]: 1=bf16 inputs, 0=fp32
  OFF_S1   = OFF_FLAG + 4,             // [b][m] 4x32 (atomic)
  OFF_GRAM = OFF_S1   + NB*MIDM,       // [b][m][m'] 4x32x32 (atomic)
  OFF_P    = OFF_GRAM + NB*MIDM*MIDM,  // [b][o]
  OFF_Q    = OFF_P    + NB*OGN,        // [b][o]
  OFF_HQ   = OFF_Q    + NB*OGN,        // fp32 [b][m][hw]
  OFF_GK   = OFF_HQ   + NB*MIDM*HWP,   // fp32 [b][m][hw]
  OFF_XBF  = OFF_GK   + NB*MIDM*HWP,   // bf16 [b][c][hw]  (NB*CC*HWP/2 floats)
  OFF_KE   = OFF_XBF  + NB*CC*HWP/2,   // bf16 [b][c][hw]
  OFF_V    = OFF_KE   + NB*CC*HWP/2,   // bf16 [b][o][hw]
  WS_TOTAL = OFF_V    + NB*OGN*HWP/2   // ~5.74M floats = 23 MB
};

__device__ __forceinline__ float bf(bf16 v) { return __bfloat162float(v); }

__device__ __forceinline__ float ldmix(const void* p, int i, bool isbf) {
  return isbf ? __bfloat162float(((const bf16*)p)[i]) : ((const float*)p)[i];
}

// ---- K-1: input dtype detector. bf16 N(0,1)*s data never has |v|>=2^14;
// fp32 data read as uint16 has ~45% of its low-mantissa words with bf16
// exponent >= 141. Deterministic inputs -> stable. ----
__global__ __launch_bounds__(256) void k_detect(const unsigned short* __restrict__ xr,
                                                float* __restrict__ ws) {
  __shared__ int bad;
  if (threadIdx.x == 0) bad = 0;
  __syncthreads();
  int cnt = 0;
  for (int i = threadIdx.x; i < 16384; i += 256) {
    unsigned short u = xr[i];
    int e = (u >> 7) & 0xFF;
    if (e >= 141) cnt++;
  }
  atomicAdd(&bad, cnt);
  __syncthreads();
  if (threadIdx.x == 0) ws[OFF_FLAG] = (bad < 64) ? 1.f : 0.f;
}

// ---- K0: convert params + x into canonical ws formats; zero accumulators ----
__global__ __launch_bounds__(256) void k_prep(
    const void* __restrict__ x,  const void* __restrict__ Wk,
    const void* __restrict__ bn1_g, const void* __restrict__ bn1_b,
    const void* __restrict__ bn1_m, const void* __restrict__ bn1_v,
    const void* __restrict__ W1, const void* __restrict__ b1,
    const void* __restrict__ bn2_g, const void* __restrict__ bn2_b,
    const void* __restrict__ bn2_m, const void* __restrict__ bn2_v,
    const void* __restrict__ W2, const void* __restrict__ b2,
    const void* __restrict__ gn_g, const void* __restrict__ gn_b,
    const void* __restrict__ Wv,
    const void* __restrict__ bnv_g, const void* __restrict__ bnv_b,
    const void* __restrict__ bnv_m, const void* __restrict__ bnv_v,
    float* __restrict__ ws) {
  const bool isbf = ws[OFF_FLAG] > 0.5f;
  int tid = blockIdx.x * blockDim.x + threadIdx.x;
  int stride = gridDim.x * blockDim.x;
  // x -> bf16 canonical copy
  bf16* xb = (bf16*)(ws + OFF_XBF);
  if (isbf) {
    const unsigned short* xu = (const unsigned short*)x;
    unsigned short* xd = (unsigned short*)xb;
    for (int i = tid; i < NB*CC*HWP; i += stride) xd[i] = xu[i];
  } else {
    const float* xf = (const float*)x;
    for (int i = tid; i < NB*CC*HWP; i += stride) xb[i] = __float2bfloat16(xf[i]);
  }
  for (int i = tid; i < CC*CC; i += stride) {
    int d = i / CC, c = i % CC;
    ws[OFF_WKT + c*CC + d] = ldmix(Wk, i, isbf);
  }
  for (int i = tid; i < MIDM*CC; i += stride) {
    int m = i / CC, c = i % CC;
    ws[OFF_W1AT + c*MIDM + m] = ldmix(W1, m*(2*CC) + c, isbf);
    ws[OFF_W1BT + c*MIDM + m] = ldmix(W1, m*(2*CC) + CC + c, isbf);
  }
  for (int i = tid; i < OGN*CC; i += stride) {
    int o = i / CC, c = i % CC;
    ws[OFF_WVT + c*OGN + o] = ldmix(Wv, i, isbf);
  }
  for (int i = tid; i < CC; i += stride) {
    float s = ldmix(bn1_g, i, isbf) / sqrtf(ldmix(bn1_v, i, isbf) + 1e-5f);
    ws[OFF_SC1 + i] = s;
    ws[OFF_SH1 + i] = ldmix(bn1_b, i, isbf) - ldmix(bn1_m, i, isbf) * s;
  }
  for (int i = tid; i < MIDM; i += stride) {
    float s = ldmix(bn2_g, i, isbf) / sqrtf(ldmix(bn2_v, i, isbf) + 1e-5f);
    ws[OFF_SC2 + i] = s;
    ws[OFF_SH2 + i] = ldmix(bn2_b, i, isbf) - ldmix(bn2_m, i, isbf) * s;
    ws[OFF_B1F + i] = ldmix(b1, i, isbf);
  }
  for (int i = tid; i < OGN; i += stride) {
    float s = ldmix(bnv_g, i, isbf) / sqrtf(ldmix(bnv_v, i, isbf) + 1e-5f);
    ws[OFF_SCV + i] = s;
    ws[OFF_SHV + i] = ldmix(bnv_b, i, isbf) - ldmix(bnv_m, i, isbf) * s;
    ws[OFF_B2F + i] = ldmix(b2, i, isbf);
    ws[OFF_GNG + i] = ldmix(gn_g, i, isbf);
    ws[OFF_GNB + i] = ldmix(gn_b, i, isbf);
  }
  for (int i = tid; i < OGN*MIDM; i += stride) ws[OFF_W2F + i] = ldmix(W2, i, isbf);
  for (int i = tid; i < NB*MIDM; i += stride) ws[OFF_S1 + i] = 0.f;
  for (int i = tid; i < NB*MIDM*MIDM; i += stride) ws[OFF_GRAM + i] = 0.f;
}

// ---- K1: ke = relu(bn1(Wk . x)) -> bf16   grid (13,16,4), 8 d/block ----
__global__ __launch_bounds__(256) void k_ke(float* __restrict__ ws) {
  int b = blockIdx.z, d0 = blockIdx.y * 8;
  int pix = blockIdx.x * 256 + threadIdx.x;
  if (pix >= HWP) return;
  const bf16* xp = (const bf16*)(ws + OFF_XBF) + (size_t)b*CC*HWP + pix;
  bf16* keb = (bf16*)(ws + OFF_KE) + (size_t)b*CC*HWP + pix;
  float acc[8];
#pragma unroll
  for (int j = 0; j < 8; j++) acc[j] = 0.f;
  for (int c = 0; c < CC; c++) {
    float xv = bf(xp[c*HWP]);
    const float* wr = ws + OFF_WKT + c*CC + d0;
#pragma unroll
    for (int j = 0; j < 8; j++) acc[j] += xv * wr[j];
  }
#pragma unroll
  for (int j = 0; j < 8; j++) {
    int d = d0 + j;
    float t = ws[OFF_SC1 + d] * acc[j] + ws[OFF_SH1 + d];
    keb[d*HWP] = __float2bfloat16(fmaxf(t, 0.f));
  }
}

// ---- K2: v = bnv(Wv . x) -> bf16   grid (13,64,4), 8 o/block ----
__global__ __launch_bounds__(256) void k_v(float* __restrict__ ws) {
  int b = blockIdx.z, o0 = blockIdx.y * 8;
  int pix = blockIdx.x * 256 + threadIdx.x;
  if (pix >= HWP) return;
  const bf16* xp = (const bf16*)(ws + OFF_XBF) + (size_t)b*CC*HWP + pix;
  bf16* vb = (bf16*)(ws + OFF_V) + ((size_t)b*OGN + o0)*HWP + pix;
  float acc[8];
#pragma unroll
  for (int j = 0; j < 8; j++) acc[j] = 0.f;
  for (int c = 0; c < CC; c++) {
    float xv = bf(xp[c*HWP]);
    const float* wr = ws + OFF_WVT + c*OGN + o0;
#pragma unroll
    for (int j = 0; j < 8; j++) acc[j] += xv * wr[j];
  }
#pragma unroll
  for (int j = 0; j < 8; j++) {
    float t = ws[OFF_SCV + o0 + j] * acc[j] + ws[OFF_SHV + o0 + j];
    vb[j*HWP] = __float2bfloat16(t);
  }
}

// ---- K3: hq = W1a . x ; gk = W1b . ke   grid (13,2,4) ----
__global__ __launch_bounds__(256) void k_hqg(float* __restrict__ ws) {
  int b = blockIdx.z, which = blockIdx.y;
  int pix = blockIdx.x * 256 + threadIdx.x;
  if (pix >= HWP) return;
  const float* Wt = ws + (which ? OFF_W1BT : OFF_W1AT);
  float* dst = ws + (which ? OFF_GK : OFF_HQ);
  const bf16* src = (const bf16*)(ws + (which ? OFF_KE : OFF_XBF))
                    + (size_t)b*CC*HWP + pix;
  float acc[MIDM];
#pragma unroll
  for (int m = 0; m < MIDM; m++) acc[m] = 0.f;
  for (int c = 0; c < CC; c++) {
    float v = bf(src[c*HWP]);
    const float* wr = Wt + c*MIDM;
#pragma unroll
    for (int m = 0; m < MIDM; m++) acc[m] += v * wr[m];
  }
#pragma unroll
  for (int m = 0; m < MIDM; m++) dst[(b*MIDM + m)*HWP + pix] = acc[m];
}

// ---- K4: per-batch S1[m], Gram[m][m'] over i=(p,hw); h recomputed on the fly.
//     grid (13,4) ----
__global__ __launch_bounds__(256) void k_gram(float* __restrict__ ws) {
  __shared__ float hs[256*33];
  int b = blockIdx.y;
  int tid = threadIdx.x;
  int pix = blockIdx.x * 256 + tid;
  bool inb = pix < HWP;
  int h0 = pix / WD, w0 = pix - h0*WD;
  const float* hqp = ws + OFF_HQ + (size_t)b*MIDM*HWP;
  const float* gkp = ws + OFF_GK + (size_t)b*MIDM*HWP;
  float base[MIDM], sc2r[MIDM];
#pragma unroll
  for (int m = 0; m < MIDM; m++) {
    float hq = inb ? hqp[m*HWP + pix] : 0.f;
    sc2r[m] = ws[OFF_SC2 + m];
    base[m] = sc2r[m]*(hq + ws[OFF_B1F + m]) + ws[OFF_SH2 + m];
  }
  int m1 = tid & 31, m2b = (tid >> 5) * 4;
  float g0=0.f, g1=0.f, g2=0.f, g3=0.f, s1=0.f;
  for (int p = 0; p < 9; p++) {
    int di = p/3 - 1, dj = p%3 - 1;
    int nh = h0 + di, nw = w0 + dj;
    bool valid = inb && ((unsigned)nh < (unsigned)WD) && ((unsigned)nw < (unsigned)WD);
    int nhw = nh*WD + nw;
    float* row = hs + tid*33;
#pragma unroll
    for (int m = 0; m < MIDM; m++) {
      float t = valid ? (sc2r[m]*gkp[m*HWP + nhw] + base[m]) : base[m];
      row[m] = inb ? fmaxf(t, 0.f) : 0.f;
    }
    __syncthreads();
    for (int k = 0; k < 256; k++) {
      float a = hs[k*33 + m1];
      g0 += a * hs[k*33 + m2b + 0];
      g1 += a * hs[k*33 + m2b + 1];
      g2 += a * hs[k*33 + m2b + 2];
      g3 += a * hs[k*33 + m2b + 3];
    }
    if (tid < MIDM) {
      for (int k = 0; k < 256; k++) s1 += hs[k*33 + tid];
    }
    __syncthreads();
  }
  float* G = ws + OFF_GRAM + (b*MIDM + m1)*MIDM + m2b;
  atomicAdd(&G[0], g0); atomicAdd(&G[1], g1);
  atomicAdd(&G[2], g2); atomicAdd(&G[3], g3);
  if (tid < MIDM) atomicAdd(ws + OFF_S1 + b*MIDM + tid, s1);
}

// ---- K5: GN stats -> per-(b,o) affine P,Q   grid (4), 512 thr ----
__global__ __launch_bounds__(512) void k_stats(float* __restrict__ ws) {
  __shared__ float Gs[MIDM*MIDM], S1s[MIDM], saS[OGN], sqS[OGN], muS[128], invS[128];
  int b = blockIdx.x;
  int o = threadIdx.x;
  Gs[o] = ws[OFF_GRAM + b*MIDM*MIDM + o];
  Gs[512 + o] = ws[OFF_GRAM + b*MIDM*MIDM + 512 + o];
  if (o < MIDM) S1s[o] = ws[OFF_S1 + b*MIDM + o];
  __syncthreads();
  float w2[MIDM];
#pragma unroll
  for (int m = 0; m < MIDM; m++) w2[m] = ws[OFF_W2F + o*MIDM + m];
  float dotS = 0.f;
#pragma unroll
  for (int m = 0; m < MIDM; m++) dotS += w2[m] * S1s[m];
  float quad = 0.f;
  for (int a = 0; a < MIDM; a++) {
    float t = 0.f;
#pragma unroll
    for (int c = 0; c < MIDM; c++) t += Gs[a*MIDM + c] * w2[c];
    quad += w2[a] * t;
  }
  float b2o = ws[OFF_B2F + o];
  const float M = 9.f * HWP;
  saS[o] = dotS + b2o * M;
  sqS[o] = quad + 2.f*b2o*dotS + b2o*b2o*M;
  __syncthreads();
  if (o < 128) {
    float sa = saS[4*o] + saS[4*o+1] + saS[4*o+2] + saS[4*o+3];
    float sq = sqS[4*o] + sqS[4*o+1] + sqS[4*o+2] + sqS[4*o+3];
    const float invN = 1.f / (4.f * M);
    float mu = sa * invN;
    float var = sq * invN - mu*mu;
    muS[o] = mu;
    invS[o] = 1.f / sqrtf(var + 1e-5f);
  }
  __syncthreads();
  int co = o >> 2;
  float alpha = ws[OFF_GNG + o] * invS[co];
  ws[OFF_P + b*OGN + o] = alpha;
  ws[OFF_Q + b*OGN + o] = alpha*b2o + ws[OFF_GNB + o] - muS[co]*alpha;
}

// ---- K6: out[b,co,hw] = sum_{gc,p} (P*(W2.h)+Q) * v_shift ; h on the fly.
//     grid (13,16,4): 32 o (8 co) per block ----
__global__ __launch_bounds__(256) void k_out(const float* __restrict__ ws,
                                             void* __restrict__ outp) {
  int b = blockIdx.z, oc0 = blockIdx.y * 32;
  int pix = blockIdx.x * 256 + threadIdx.x;
  if (pix >= HWP) return;
  const bool isbf = ws[OFF_FLAG] > 0.5f;
  int h0 = pix / WD, w0 = pix - h0*WD;
  const float* hqp = ws + OFF_HQ + (size_t)b*MIDM*HWP;
  const float* gkp = ws + OFF_GK + (size_t)b*MIDM*HWP;
  const bf16* vb = (const bf16*)(ws + OFF_V) + ((size_t)b*OGN + oc0)*HWP;
  const float* W2f = ws + OFF_W2F + oc0*MIDM;
  const float* Pp = ws + OFF_P + b*OGN + oc0;
  const float* Qp = ws + OFF_Q + b*OGN + oc0;
  float base[MIDM], sc2r[MIDM];
#pragma unroll
  for (int m = 0; m < MIDM; m++) {
    sc2r[m] = ws[OFF_SC2 + m];
    base[m] = sc2r[m]*(hqp[m*HWP + pix] + ws[OFF_B1F + m]) + ws[OFF_SH2 + m];
  }
  float acc[8];
#pragma unroll
  for (int j = 0; j < 8; j++) acc[j] = 0.f;
  for (int p = 0; p < 9; p++) {
    int di = p/3 - 1, dj = p%3 - 1;
    int nh = h0 + di, nw = w0 + dj;
    bool valid = ((unsigned)nh < (unsigned)WD) && ((unsigned)nw < (unsigned)WD);
    if (!valid) continue;   // V is zero-padded -> term is exactly 0
    int nhw = nh*WD + nw;
    float h[MIDM];
#pragma unroll
    for (int m = 0; m < MIDM; m++)
      h[m] = fmaxf(sc2r[m]*gkp[m*HWP + nhw] + base[m], 0.f);
#pragma unroll
    for (int ol = 0; ol < 32; ol++) {
      const float* wr = W2f + ol*MIDM;
      float s = 0.f;
#pragma unroll
      for (int m = 0; m < MIDM; m++) s += wr[m] * h[m];
      float vv = bf(vb[ol*HWP + nhw]);
      acc[ol >> 2] += (Pp[ol]*s + Qp[ol]) * vv;
    }
  }
  int co0 = oc0 >> 2;
#pragma unroll
  for (int j = 0; j < 8; j++) {
    size_t oidx = ((size_t)b*128 + co0 + j)*HWP + pix;
    if (isbf) ((bf16*)outp)[oidx] = __float2bfloat16(acc[j]);
    else      ((float*)outp)[oidx] = acc[j];
  }
}

extern "C" void kernel_launch(void* const* d_in, const int* in_sizes, int n_in,
                              void* d_out, int out_size, void* d_ws, size_t ws_size,
                              hipStream_t stream) {
  float* ws = (float*)d_ws;
  hipLaunchKernelGGL(k_detect, dim3(1), dim3(256), 0, stream,
                     (const unsigned short*)d_in[0], ws);
  hipLaunchKernelGGL(k_prep, dim3(64), dim3(256), 0, stream,
                     d_in[0], d_in[1], d_in[2], d_in[3], d_in[4], d_in[5],
                     d_in[6], d_in[7], d_in[8], d_in[9], d_in[10], d_in[11],
                     d_in[12], d_in[13], d_in[14], d_in[15], d_in[16],
                     d_in[17], d_in[18], d_in[19], d_in[20], ws);
  hipLaunchKernelGGL(k_ke,   dim3(13, 16, 4), dim3(256), 0, stream, ws);
  hipLaunchKernelGGL(k_v,    dim3(13, 64, 4), dim3(256), 0, stream, ws);
  hipLaunchKernelGGL(k_hqg,  dim3(13, 2, 4),  dim3(256), 0, stream, ws);
  hipLaunchKernelGGL(k_gram, dim3(13, 4),     dim3(256), 0, stream, ws);
  hipLaunchKernelGGL(k_stats,dim3(4),         dim3(512), 0, stream, ws);
  hipLaunchKernelGGL(k_out,  dim3(13, 16, 4), dim3(256), 0, stream, ws, d_out);
}

// Round 3
// 341.780 us; speedup vs baseline: 1.5764x; 1.5764x over previous
//
#include <hip/hip_runtime.h>
#include <hip/hip_bf16.h>

typedef __hip_bfloat16 bf16;
typedef __attribute__((ext_vector_type(8))) short short8;   // 8 bf16 = 4 VGPR
typedef __attribute__((ext_vector_type(4))) float f32x4;

#define HWP 3136
#define WD 56
#define CC 128
#define MIDM 32
#define OGN 512
#define NB 4

// workspace offsets in FLOAT units (all 16B-aligned)
enum : int {
  OFF_FLAG = 0,                          // [4] flag[0]: 1=bf16 inputs
  OFF_W2F  = 4,                          // fp32 [o][m] 512x32 (for stats)
  OFF_SC2  = OFF_W2F + OGN*MIDM,         // [32]
  OFF_SH2  = OFF_SC2 + MIDM,             // [32]
  OFF_B1F  = OFF_SH2 + MIDM,             // [32]
  OFF_B2F  = OFF_B1F + MIDM,             // [512]
  OFF_GNG  = OFF_B2F + OGN,              // [512]
  OFF_GNB  = OFF_GNG + OGN,              // [512]
  OFF_S1   = OFF_GNB + OGN,              // [b][32] atomics
  OFF_GRAM = OFF_S1 + NB*MIDM,           // [b][32][32] atomics
  OFF_PQ   = OFF_GRAM + NB*MIDM*MIDM,    // float2 [b][512]
  OFF_SS1  = OFF_PQ + NB*OGN*2,          // float2 [128] bn1 scale/shift
  OFF_SSV  = OFF_SS1 + CC*2,             // float2 [512] bnv scale/shift
  OFF_WKB  = OFF_SSV + OGN*2,            // bf16 [d][c] 128x128
  OFF_WVB  = OFF_WKB + CC*CC/2,          // bf16 [o][c] 512x128
  OFF_W1AB = OFF_WVB + OGN*CC/2,         // bf16 [m][c] 32x128
  OFF_W1BB = OFF_W1AB + MIDM*CC/2,       // bf16 [m][c] 32x128
  OFF_W2B  = OFF_W1BB + MIDM*CC/2,       // bf16 [o][m] 512x32
  OFF_HQT  = OFF_W2B + OGN*MIDM/2,       // bf16 [b][pix][m]
  OFF_GKT  = OFF_HQT + NB*HWP*MIDM/2,    // bf16 [b][pix][m]
  OFF_VT   = OFF_GKT + NB*HWP*MIDM/2,    // bf16 [b][pix][o]
  OFF_R1   = OFF_VT + NB*HWP*OGN/2,      // union region
  OFF_XT   = OFF_R1,                     // bf16 [b][pix][c]   (phase 1)
  OFF_KET  = OFF_R1 + NB*HWP*CC/2,       // bf16 [b][pix][d]   (phase 1)
  OFF_HS   = OFF_R1,                     // bf16 [b][p][pix][m] (phase 2)
  WS_TOTAL = OFF_R1 + NB*9*HWP*MIDM/2    // ~5.5M floats = 22 MB
};

__device__ __forceinline__ float b2f(unsigned short u) {
  bf16 h; *(unsigned short*)&h = u; return __bfloat162float(h);
}
__device__ __forceinline__ unsigned short f2b(float f) {
  bf16 h = __float2bfloat16(f); return *(unsigned short*)&h;
}
__device__ __forceinline__ float ldmix(const void* p, size_t i, bool isbf) {
  return isbf ? __bfloat162float(((const bf16*)p)[i]) : ((const float*)p)[i];
}
__device__ __forceinline__ f32x4 mfma16(short8 a, short8 b, f32x4 c) {
  return __builtin_amdgcn_mfma_f32_16x16x32_bf16(a, b, c, 0, 0, 0);
}

// ---- dtype detector (bf16 N(0,s) never has exponent>=141; fp32-as-u16 does) ----
__global__ __launch_bounds__(256) void k_detect(const unsigned short* __restrict__ xr,
                                                float* __restrict__ ws) {
  __shared__ int bad;
  if (threadIdx.x == 0) bad = 0;
  __syncthreads();
  int cnt = 0;
  for (int i = threadIdx.x; i < 16384; i += 256) {
    int e = (xr[i] >> 7) & 0xFF;
    if (e >= 141) cnt++;
  }
  atomicAdd(&bad, cnt);
  __syncthreads();
  if (threadIdx.x == 0) ws[OFF_FLAG] = (bad < 64) ? 1.f : 0.f;
}

// ---- params: fold BN, cast weights to bf16, zero accumulators ----
__global__ __launch_bounds__(256) void k_prep(
    const void* __restrict__ Wk,
    const void* __restrict__ bn1_g, const void* __restrict__ bn1_b,
    const void* __restrict__ bn1_m, const void* __restrict__ bn1_v,
    const void* __restrict__ W1, const void* __restrict__ b1,
    const void* __restrict__ bn2_g, const void* __restrict__ bn2_b,
    const void* __restrict__ bn2_m, const void* __restrict__ bn2_v,
    const void* __restrict__ W2, const void* __restrict__ b2,
    const void* __restrict__ gn_g, const void* __restrict__ gn_b,
    const void* __restrict__ Wv,
    const void* __restrict__ bnv_g, const void* __restrict__ bnv_b,
    const void* __restrict__ bnv_m, const void* __restrict__ bnv_v,
    float* __restrict__ ws) {
  const bool isbf = ws[OFF_FLAG] > 0.5f;
  int tid = blockIdx.x * blockDim.x + threadIdx.x;
  int stride = gridDim.x * blockDim.x;
  unsigned short* wkb = (unsigned short*)(ws + OFF_WKB);
  unsigned short* wvb = (unsigned short*)(ws + OFF_WVB);
  unsigned short* w1ab = (unsigned short*)(ws + OFF_W1AB);
  unsigned short* w1bb = (unsigned short*)(ws + OFF_W1BB);
  unsigned short* w2b = (unsigned short*)(ws + OFF_W2B);
  float2* ss1 = (float2*)(ws + OFF_SS1);
  float2* ssv = (float2*)(ws + OFF_SSV);
  for (int i = tid; i < CC*CC; i += stride) wkb[i] = f2b(ldmix(Wk, i, isbf));
  for (int i = tid; i < OGN*CC; i += stride) wvb[i] = f2b(ldmix(Wv, i, isbf));
  for (int i = tid; i < MIDM*CC; i += stride) {
    int m = i / CC, c = i % CC;
    w1ab[i] = f2b(ldmix(W1, (size_t)m*(2*CC) + c, isbf));
    w1bb[i] = f2b(ldmix(W1, (size_t)m*(2*CC) + CC + c, isbf));
  }
  for (int i = tid; i < OGN*MIDM; i += stride) {
    float w = ldmix(W2, i, isbf);
    ws[OFF_W2F + i] = w;
    w2b[i] = f2b(w);
  }
  for (int i = tid; i < CC; i += stride) {
    float s = ldmix(bn1_g, i, isbf) / sqrtf(ldmix(bn1_v, i, isbf) + 1e-5f);
    ss1[i] = make_float2(s, ldmix(bn1_b, i, isbf) - ldmix(bn1_m, i, isbf) * s);
  }
  for (int i = tid; i < MIDM; i += stride) {
    float s = ldmix(bn2_g, i, isbf) / sqrtf(ldmix(bn2_v, i, isbf) + 1e-5f);
    ws[OFF_SC2 + i] = s;
    ws[OFF_SH2 + i] = ldmix(bn2_b, i, isbf) - ldmix(bn2_m, i, isbf) * s;
    ws[OFF_B1F + i] = ldmix(b1, i, isbf);
  }
  for (int i = tid; i < OGN; i += stride) {
    float s = ldmix(bnv_g, i, isbf) / sqrtf(ldmix(bnv_v, i, isbf) + 1e-5f);
    ssv[i] = make_float2(s, ldmix(bnv_b, i, isbf) - ldmix(bnv_m, i, isbf) * s);
    ws[OFF_B2F + i] = ldmix(b2, i, isbf);
    ws[OFF_GNG + i] = ldmix(gn_g, i, isbf);
    ws[OFF_GNB + i] = ldmix(gn_b, i, isbf);
  }
  for (int i = tid; i < NB*MIDM; i += stride) ws[OFF_S1 + i] = 0.f;
  for (int i = tid; i < NB*MIDM*MIDM; i += stride) ws[OFF_GRAM + i] = 0.f;
}

// ---- x -> xt[b][pix][c] bf16, LDS-tiled transpose. grid (98,4) ----
__global__ __launch_bounds__(256) void k_tx(const void* __restrict__ x,
                                            float* __restrict__ ws) {
  __shared__ unsigned short tile[32*130];
  const bool isbf = ws[OFF_FLAG] > 0.5f;
  int b = blockIdx.y, pix0 = blockIdx.x * 32;
#pragma unroll
  for (int k = 0; k < 16; k++) {
    int idx = threadIdx.x + k*256;
    int c = idx >> 5, pl = idx & 31;
    tile[pl*130 + c] = f2b(ldmix(x, ((size_t)b*CC + c)*HWP + pix0 + pl, isbf));
  }
  __syncthreads();
  unsigned short* xt = (unsigned short*)(ws + OFF_XT);
#pragma unroll
  for (int k = 0; k < 16; k++) {
    int idx = threadIdx.x + k*256;
    int c = idx & 127, pl = idx >> 7;
    xt[((size_t)b*HWP + pix0 + pl)*CC + c] = tile[pl*130 + c];
  }
}

// ---- ke_t[pix][d] = relu(bn1(Wk.x)) via MFMA. grid (49,1,4) ----
__global__ __launch_bounds__(256) void k_ke(float* __restrict__ ws) {
  int b = blockIdx.z;
  int w = threadIdx.x >> 6, lane = threadIdx.x & 63;
  int q = lane >> 4, l16 = lane & 15;
  int pix = blockIdx.x*64 + w*16 + l16;
  const unsigned short* xt = (const unsigned short*)(ws + OFF_XT) + ((size_t)b*HWP + pix)*CC;
  short8 B[4];
#pragma unroll
  for (int kk = 0; kk < 4; kk++) B[kk] = *(const short8*)(xt + kk*32 + q*8);
  const unsigned short* wkb = (const unsigned short*)(ws + OFF_WKB);
  const float2* ss = (const float2*)(ws + OFF_SS1);
  unsigned short* ket = (unsigned short*)(ws + OFF_KET) + ((size_t)b*HWP + pix)*CC;
#pragma unroll
  for (int ot = 0; ot < 8; ot++) {
    int drow = ot*16 + l16;
    f32x4 c = {0.f, 0.f, 0.f, 0.f};
#pragma unroll
    for (int kk = 0; kk < 4; kk++)
      c = mfma16(*(const short8*)(wkb + (size_t)drow*CC + kk*32 + q*8), B[kk], c);
    int d0 = ot*16 + q*4;
    ushort4 st;
    { float2 s = ss[d0+0]; st.x = f2b(fmaxf(s.x*c[0] + s.y, 0.f)); }
    { float2 s = ss[d0+1]; st.y = f2b(fmaxf(s.x*c[1] + s.y, 0.f)); }
    { float2 s = ss[d0+2]; st.z = f2b(fmaxf(s.x*c[2] + s.y, 0.f)); }
    { float2 s = ss[d0+3]; st.w = f2b(fmaxf(s.x*c[3] + s.y, 0.f)); }
    *(ushort4*)(ket + d0) = st;
  }
}

// ---- v_t[pix][o] = bnv(Wv.x) via MFMA. grid (49,4,4) ----
__global__ __launch_bounds__(256) void k_v(float* __restrict__ ws) {
  int b = blockIdx.z, by = blockIdx.y;
  int w = threadIdx.x >> 6, lane = threadIdx.x & 63;
  int q = lane >> 4, l16 = lane & 15;
  int pix = blockIdx.x*64 + w*16 + l16;
  const unsigned short* xt = (const unsigned short*)(ws + OFF_XT) + ((size_t)b*HWP + pix)*CC;
  short8 B[4];
#pragma unroll
  for (int kk = 0; kk < 4; kk++) B[kk] = *(const short8*)(xt + kk*32 + q*8);
  const unsigned short* wvb = (const unsigned short*)(ws + OFF_WVB);
  const float2* ss = (const float2*)(ws + OFF_SSV);
  unsigned short* vt = (unsigned short*)(ws + OFF_VT) + ((size_t)b*HWP + pix)*OGN;
#pragma unroll
  for (int ot = 0; ot < 8; ot++) {
    int orow = by*128 + ot*16 + l16;
    f32x4 c = {0.f, 0.f, 0.f, 0.f};
#pragma unroll
    for (int kk = 0; kk < 4; kk++)
      c = mfma16(*(const short8*)(wvb + (size_t)orow*CC + kk*32 + q*8), B[kk], c);
    int o0 = by*128 + ot*16 + q*4;
    ushort4 st;
    { float2 s = ss[o0+0]; st.x = f2b(s.x*c[0] + s.y); }
    { float2 s = ss[o0+1]; st.y = f2b(s.x*c[1] + s.y); }
    { float2 s = ss[o0+2]; st.z = f2b(s.x*c[2] + s.y); }
    { float2 s = ss[o0+3]; st.w = f2b(s.x*c[3] + s.y); }
    *(ushort4*)(vt + o0) = st;
  }
}

// ---- hq_t[pix][m] = W1a.x ; gk_t[pix][m] = W1b.ke  (bf16). grid (49,1,4) ----
__global__ __launch_bounds__(256) void k_hqg(float* __restrict__ ws) {
  int b = blockIdx.z;
  int w = threadIdx.x >> 6, lane = threadIdx.x & 63;
  int q = lane >> 4, l16 = lane & 15;
  int pix = blockIdx.x*64 + w*16 + l16;
  const unsigned short* xt = (const unsigned short*)(ws + OFF_XT) + ((size_t)b*HWP + pix)*CC;
  const unsigned short* ket = (const unsigned short*)(ws + OFF_KET) + ((size_t)b*HWP + pix)*CC;
  short8 Bx[4], Bk[4];
#pragma unroll
  for (int kk = 0; kk < 4; kk++) {
    Bx[kk] = *(const short8*)(xt + kk*32 + q*8);
    Bk[kk] = *(const short8*)(ket + kk*32 + q*8);
  }
  const unsigned short* w1a = (const unsigned short*)(ws + OFF_W1AB);
  const unsigned short* w1b = (const unsigned short*)(ws + OFF_W1BB);
  unsigned short* hqt = (unsigned short*)(ws + OFF_HQT) + ((size_t)b*HWP + pix)*MIDM;
  unsigned short* gkt = (unsigned short*)(ws + OFF_GKT) + ((size_t)b*HWP + pix)*MIDM;
#pragma unroll
  for (int mt = 0; mt < 2; mt++) {
    int mrow = mt*16 + l16;
    f32x4 ch = {0.f,0.f,0.f,0.f}, cg = {0.f,0.f,0.f,0.f};
#pragma unroll
    for (int kk = 0; kk < 4; kk++) {
      ch = mfma16(*(const short8*)(w1a + (size_t)mrow*CC + kk*32 + q*8), Bx[kk], ch);
      cg = mfma16(*(const short8*)(w1b + (size_t)mrow*CC + kk*32 + q*8), Bk[kk], cg);
    }
    int m0 = mt*16 + q*4;
    ushort4 sh, sg;
    sh.x = f2b(ch[0]); sh.y = f2b(ch[1]); sh.z = f2b(ch[2]); sh.w = f2b(ch[3]);
    sg.x = f2b(cg[0]); sg.y = f2b(cg[1]); sg.z = f2b(cg[2]); sg.w = f2b(cg[3]);
    *(ushort4*)(hqt + m0) = sh;
    *(ushort4*)(gkt + m0) = sg;
  }
}

// ---- hs[b][p][pix][m] = relu(bn2(hq + shift(gk) + b1)) bf16. grid (13,9,4) ----
__global__ __launch_bounds__(256) void k_h(float* __restrict__ ws) {
  int b = blockIdx.z, p = blockIdx.y;
  int pix = blockIdx.x*256 + threadIdx.x;
  if (pix >= HWP) return;
  int h0 = pix / WD, w0 = pix - h0*WD;
  int nh = h0 + p/3 - 1, nw = w0 + p%3 - 1;
  bool valid = ((unsigned)nh < (unsigned)WD) && ((unsigned)nw < (unsigned)WD);
  int npix = nh*WD + nw;
  const unsigned short* hq = (const unsigned short*)(ws + OFF_HQT) + ((size_t)b*HWP + pix)*MIDM;
  const unsigned short* gk = (const unsigned short*)(ws + OFF_GKT) + ((size_t)b*HWP + npix)*MIDM;
  unsigned short* hd = (unsigned short*)(ws + OFF_HS) + ((size_t)((b*9 + p))*HWP + pix)*MIDM;
  float hv[MIDM];
#pragma unroll
  for (int k = 0; k < 4; k++) {
    short8 t = *(const short8*)(hq + k*8);
#pragma unroll
    for (int j = 0; j < 8; j++) hv[k*8+j] = b2f((unsigned short)t[j]);
  }
  if (valid) {
#pragma unroll
    for (int k = 0; k < 4; k++) {
      short8 t = *(const short8*)(gk + k*8);
#pragma unroll
      for (int j = 0; j < 8; j++) hv[k*8+j] += b2f((unsigned short)t[j]);
    }
  }
#pragma unroll
  for (int k = 0; k < 8; k++) {
    ushort4 st;
    float t0, t1, t2, t3;
    int m = k*4;
    t0 = fmaxf(ws[OFF_SC2+m+0]*(hv[m+0] + ws[OFF_B1F+m+0]) + ws[OFF_SH2+m+0], 0.f);
    t1 = fmaxf(ws[OFF_SC2+m+1]*(hv[m+1] + ws[OFF_B1F+m+1]) + ws[OFF_SH2+m+1], 0.f);
    t2 = fmaxf(ws[OFF_SC2+m+2]*(hv[m+2] + ws[OFF_B1F+m+2]) + ws[OFF_SH2+m+2], 0.f);
    t3 = fmaxf(ws[OFF_SC2+m+3]*(hv[m+3] + ws[OFF_B1F+m+3]) + ws[OFF_SH2+m+3], 0.f);
    st.x = f2b(t0); st.y = f2b(t1); st.z = f2b(t2); st.w = f2b(t3);
    *(ushort4*)(hd + m) = st;
  }
}

// ---- Gram + S1 via MFMA (A==B from hs). grid (49,4) ----
__global__ __launch_bounds__(256) void k_gram(float* __restrict__ ws) {
  int b = blockIdx.y;
  int w = threadIdx.x >> 6, lane = threadIdx.x & 63;
  int q = lane >> 4, l16 = lane & 15;
  int g = blockIdx.x*4 + w;   // 0..195
  const unsigned short* hsb = (const unsigned short*)(ws + OFF_HS) + (size_t)b*9*HWP*MIDM;
  f32x4 gLL = {0,0,0,0}, gLH = {0,0,0,0}, gHL = {0,0,0,0}, gHH = {0,0,0,0};
  f32x4 sL = {0,0,0,0}, sH = {0,0,0,0};
  short8 ones;
#pragma unroll
  for (int j = 0; j < 8; j++) ones[j] = (short)0x3F80;
  for (int ci = g; ci < 882; ci += 196) {
    int p = ci / 98, ch = ci - p*98;
    int pix0 = ch*32;
    const unsigned short* base = hsb + ((size_t)p*HWP + pix0)*MIDM;
    short8 alo, ahi;
#pragma unroll
    for (int j = 0; j < 8; j++) {
      const unsigned short* row = base + (q*8 + j)*MIDM;
      alo[j] = (short)row[l16];
      ahi[j] = (short)row[l16 + 16];
    }
    gLL = mfma16(alo, alo, gLL);
    gLH = mfma16(alo, ahi, gLH);
    gHL = mfma16(ahi, alo, gHL);
    gHH = mfma16(ahi, ahi, gHH);
    sL = mfma16(alo, ones, sL);
    sH = mfma16(ahi, ones, sH);
  }
  float* G = ws + OFF_GRAM + b*MIDM*MIDM;
#pragma unroll
  for (int r = 0; r < 4; r++) {
    atomicAdd(&G[(q*4 + r)*MIDM + l16],        gLL[r]);
    atomicAdd(&G[(q*4 + r)*MIDM + 16 + l16],   gLH[r]);
    atomicAdd(&G[(16 + q*4 + r)*MIDM + l16],      gHL[r]);
    atomicAdd(&G[(16 + q*4 + r)*MIDM + 16 + l16], gHH[r]);
  }
  if (l16 == 0) {
#pragma unroll
    for (int r = 0; r < 4; r++) {
      atomicAdd(&ws[OFF_S1 + b*MIDM + q*4 + r],      sL[r]);
      atomicAdd(&ws[OFF_S1 + b*MIDM + 16 + q*4 + r], sH[r]);
    }
  }
}

// ---- GN stats -> PQ float2 per (b,o). grid (4) x 512 ----
__global__ __launch_bounds__(512) void k_stats(float* __restrict__ ws) {
  __shared__ float Gs[MIDM*MIDM], S1s[MIDM], saS[OGN], sqS[OGN], muS[128], invS[128];
  int b = blockIdx.x, o = threadIdx.x;
  Gs[o] = ws[OFF_GRAM + b*MIDM*MIDM + o];
  Gs[512 + o] = ws[OFF_GRAM + b*MIDM*MIDM + 512 + o];
  if (o < MIDM) S1s[o] = ws[OFF_S1 + b*MIDM + o];
  __syncthreads();
  float w2[MIDM];
#pragma unroll
  for (int m = 0; m < MIDM; m++) w2[m] = ws[OFF_W2F + o*MIDM + m];
  float dotS = 0.f;
#pragma unroll
  for (int m = 0; m < MIDM; m++) dotS += w2[m] * S1s[m];
  float quad = 0.f;
  for (int a = 0; a < MIDM; a++) {
    float t = 0.f;
#pragma unroll
    for (int c = 0; c < MIDM; c++) t += Gs[a*MIDM + c] * w2[c];
    quad += w2[a] * t;
  }
  float b2o = ws[OFF_B2F + o];
  const float M = 9.f * HWP;
  saS[o] = dotS + b2o * M;
  sqS[o] = quad + 2.f*b2o*dotS + b2o*b2o*M;
  __syncthreads();
  if (o < 128) {
    float sa = saS[4*o] + saS[4*o+1] + saS[4*o+2] + saS[4*o+3];
    float sq = sqS[4*o] + sqS[4*o+1] + sqS[4*o+2] + sqS[4*o+3];
    const float invN = 1.f / (4.f * M);
    float mu = sa * invN;
    float var = sq * invN - mu*mu;
    muS[o] = mu;
    invS[o] = 1.f / sqrtf(var + 1e-5f);
  }
  __syncthreads();
  int co = o >> 2;
  float alpha = ws[OFF_GNG + o] * invS[co];
  ((float2*)(ws + OFF_PQ))[b*OGN + o] =
      make_float2(alpha, alpha*b2o + ws[OFF_GNB + o] - muS[co]*alpha);
}

// ---- fused epilogue via MFMA: out[b,co,pix] = sum_{p,o in co} (P*(W2.h)+Q)*v
//     grid (49,4,4) ----
__global__ __launch_bounds__(256) void k_out(const float* __restrict__ ws,
                                             void* __restrict__ outp) {
  int b = blockIdx.z, by = blockIdx.y;
  int w = threadIdx.x >> 6, lane = threadIdx.x & 63;
  int q = lane >> 4, l16 = lane & 15;
  int pix = blockIdx.x*64 + w*16 + l16;
  int h0 = pix / WD, w0 = pix - h0*WD;
  const bool isbf = ws[OFF_FLAG] > 0.5f;
  const unsigned short* w2b = (const unsigned short*)(ws + OFF_W2B);
  short8 A[8];
#pragma unroll
  for (int ot = 0; ot < 8; ot++) {
    int orow = by*128 + ot*16 + l16;
    A[ot] = *(const short8*)(w2b + (size_t)orow*MIDM + q*8);
  }
  const float2* pq = (const float2*)(ws + OFF_PQ) + b*OGN;
  const unsigned short* vt = (const unsigned short*)(ws + OFF_VT) + (size_t)b*HWP*OGN;
  const unsigned short* hsb = (const unsigned short*)(ws + OFF_HS) + (size_t)b*9*HWP*MIDM;
  float acc[8];
#pragma unroll
  for (int j = 0; j < 8; j++) acc[j] = 0.f;
  for (int p = 0; p < 9; p++) {
    int nh = h0 + p/3 - 1, nw = w0 + p%3 - 1;
    bool valid = ((unsigned)nh < (unsigned)WD) && ((unsigned)nw < (unsigned)WD);
    int npix = valid ? (nh*WD + nw) : 0;
    short8 B = *(const short8*)(hsb + ((size_t)p*HWP + pix)*MIDM + q*8);
#pragma unroll
    for (int ot = 0; ot < 8; ot++) {
      f32x4 c = {0.f, 0.f, 0.f, 0.f};
      c = mfma16(A[ot], B, c);
      int o0 = by*128 + ot*16 + q*4;
      float v0 = 0.f, v1 = 0.f, v2 = 0.f, v3 = 0.f;
      if (valid) {
        ushort4 vv = *(const ushort4*)(vt + (size_t)npix*OGN + o0);
        v0 = b2f(vv.x); v1 = b2f(vv.y); v2 = b2f(vv.z); v3 = b2f(vv.w);
      }
      float2 p0 = pq[o0+0], p1 = pq[o0+1], p2 = pq[o0+2], p3 = pq[o0+3];
      acc[ot] += (p0.x*c[0] + p0.y)*v0 + (p1.x*c[1] + p1.y)*v1
               + (p2.x*c[2] + p2.y)*v2 + (p3.x*c[3] + p3.y)*v3;
    }
  }
#pragma unroll
  for (int ot = 0; ot < 8; ot++) {
    int co = by*32 + ot*4 + q;
    size_t oidx = ((size_t)b*128 + co)*HWP + pix;
    if (isbf) ((unsigned short*)outp)[oidx] = f2b(acc[ot]);
    else      ((float*)outp)[oidx] = acc[ot];
  }
}

extern "C" void kernel_launch(void* const* d_in, const int* in_sizes, int n_in,
                              void* d_out, int out_size, void* d_ws, size_t ws_size,
                              hipStream_t stream) {
  float* ws = (float*)d_ws;
  hipLaunchKernelGGL(k_detect, dim3(1), dim3(256), 0, stream,
                     (const unsigned short*)d_in[0], ws);
  hipLaunchKernelGGL(k_prep, dim3(64), dim3(256), 0, stream,
                     d_in[1], d_in[2], d_in[3], d_in[4], d_in[5],
                     d_in[6], d_in[7], d_in[8], d_in[9], d_in[10], d_in[11],
                     d_in[12], d_in[13], d_in[14], d_in[15], d_in[16],
                     d_in[17], d_in[18], d_in[19], d_in[20], ws);
  hipLaunchKernelGGL(k_tx,   dim3(98, 4),     dim3(256), 0, stream, d_in[0], ws);
  hipLaunchKernelGGL(k_ke,   dim3(49, 1, 4),  dim3(256), 0, stream, ws);
  hipLaunchKernelGGL(k_v,    dim3(49, 4, 4),  dim3(256), 0, stream, ws);
  hipLaunchKernelGGL(k_hqg,  dim3(49, 1, 4),  dim3(256), 0, stream, ws);
  hipLaunchKernelGGL(k_h,    dim3(13, 9, 4),  dim3(256), 0, stream, ws);
  hipLaunchKernelGGL(k_gram, dim3(49, 4),     dim3(256), 0, stream, ws);
  hipLaunchKernelGGL(k_stats,dim3(4),         dim3(512), 0, stream, ws);
  hipLaunchKernelGGL(k_out,  dim3(49, 4, 4),  dim3(256), 0, stream, ws, d_out);
}

// Round 4
// 282.229 us; speedup vs baseline: 1.9091x; 1.2110x over previous
//
#include <hip/hip_runtime.h>
#include <hip/hip_bf16.h>

typedef __hip_bfloat16 bf16;
typedef __attribute__((ext_vector_type(8))) short short8;   // 8 bf16 = 4 VGPR
typedef __attribute__((ext_vector_type(4))) float f32x4;

#define HWP 3136
#define WD 56
#define CC 128
#define MIDM 32
#define OGN 512
#define NB 4

// workspace offsets in FLOAT units (all 16B-aligned)
enum : int {
  OFF_FLAG = 0,                          // [4] flag[0]: 1=bf16 inputs
  OFF_W2F  = 4,                          // fp32 [o][m] 512x32 (for stats)
  OFF_SC2  = OFF_W2F + OGN*MIDM,         // [32]
  OFF_SH2  = OFF_SC2 + MIDM,             // [32]
  OFF_B1F  = OFF_SH2 + MIDM,             // [32]
  OFF_B2F  = OFF_B1F + MIDM,             // [512]
  OFF_GNG  = OFF_B2F + OGN,              // [512]
  OFF_GNB  = OFF_GNG + OGN,              // [512]
  OFF_S1   = OFF_GNB + OGN,              // [b][32] atomics
  OFF_GRAM = OFF_S1 + NB*MIDM,           // [b][32][32] atomics
  OFF_PQ   = OFF_GRAM + NB*MIDM*MIDM,    // float2 [b][512]
  OFF_SS1  = OFF_PQ + NB*OGN*2,          // float2 [128] bn1 scale/shift
  OFF_SSV  = OFF_SS1 + CC*2,             // float2 [512] bnv scale/shift
  OFF_WKB  = OFF_SSV + OGN*2,            // bf16 [d][c] 128x128
  OFF_WVB  = OFF_WKB + CC*CC/2,          // bf16 [o][c] 512x128
  OFF_W1AB = OFF_WVB + OGN*CC/2,         // bf16 [m][c] 32x128
  OFF_W1BB = OFF_W1AB + MIDM*CC/2,       // bf16 [m][c] 32x128
  OFF_W2B  = OFF_W1BB + MIDM*CC/2,       // bf16 [o][m] 512x32
  OFF_HQT  = OFF_W2B + OGN*MIDM/2,       // bf16 [b][pix][m]
  OFF_GKT  = OFF_HQT + NB*HWP*MIDM/2,    // bf16 [b][pix][m]
  OFF_VT   = OFF_GKT + NB*HWP*MIDM/2,    // bf16 [b][pix][o]; becomes P*v
  OFF_WQ   = OFF_VT + NB*HWP*OGN/2,      // bf16 [b][pix][co]  w = sum_gc Q*v
  OFF_WSUM = OFF_WQ + NB*HWP*CC/2,       // bf16 [b][pix][co]  3x3 box of w
  OFF_R1   = OFF_WSUM + NB*HWP*CC/2,     // union region
  OFF_XT   = OFF_R1,                     // bf16 [b][pix][c]    (phase 1)
  OFF_HS   = OFF_R1,                     // bf16 [b][p][pix][m] (phase 2)
  WS_TOTAL = OFF_R1 + NB*9*HWP*MIDM/2    // ~29 MB total
};

__device__ __forceinline__ float b2f(unsigned short u) {
  bf16 h; *(unsigned short*)&h = u; return __bfloat162float(h);
}
__device__ __forceinline__ unsigned short f2b(float f) {
  bf16 h = __float2bfloat16(f); return *(unsigned short*)&h;
}
__device__ __forceinline__ float ldmix(const void* p, size_t i, bool isbf) {
  return isbf ? __bfloat162float(((const bf16*)p)[i]) : ((const float*)p)[i];
}
__device__ __forceinline__ f32x4 mfma16(short8 a, short8 b, f32x4 c) {
  return __builtin_amdgcn_mfma_f32_16x16x32_bf16(a, b, c, 0, 0, 0);
}

// ---- dtype detector ----
__global__ __launch_bounds__(256) void k_detect(const unsigned short* __restrict__ xr,
                                                float* __restrict__ ws) {
  __shared__ int bad;
  if (threadIdx.x == 0) bad = 0;
  __syncthreads();
  int cnt = 0;
  for (int i = threadIdx.x; i < 16384; i += 256) {
    int e = (xr[i] >> 7) & 0xFF;
    if (e >= 141) cnt++;
  }
  atomicAdd(&bad, cnt);
  __syncthreads();
  if (threadIdx.x == 0) ws[OFF_FLAG] = (bad < 64) ? 1.f : 0.f;
}

// ---- params: fold BN, cast weights to bf16, zero accumulators ----
__global__ __launch_bounds__(256) void k_prep(
    const void* __restrict__ Wk,
    const void* __restrict__ bn1_g, const void* __restrict__ bn1_b,
    const void* __restrict__ bn1_m, const void* __restrict__ bn1_v,
    const void* __restrict__ W1, const void* __restrict__ b1,
    const void* __restrict__ bn2_g, const void* __restrict__ bn2_b,
    const void* __restrict__ bn2_m, const void* __restrict__ bn2_v,
    const void* __restrict__ W2, const void* __restrict__ b2,
    const void* __restrict__ gn_g, const void* __restrict__ gn_b,
    const void* __restrict__ Wv,
    const void* __restrict__ bnv_g, const void* __restrict__ bnv_b,
    const void* __restrict__ bnv_m, const void* __restrict__ bnv_v,
    float* __restrict__ ws) {
  const bool isbf = ws[OFF_FLAG] > 0.5f;
  int tid = blockIdx.x * blockDim.x + threadIdx.x;
  int stride = gridDim.x * blockDim.x;
  unsigned short* wkb = (unsigned short*)(ws + OFF_WKB);
  unsigned short* wvb = (unsigned short*)(ws + OFF_WVB);
  unsigned short* w1ab = (unsigned short*)(ws + OFF_W1AB);
  unsigned short* w1bb = (unsigned short*)(ws + OFF_W1BB);
  unsigned short* w2b = (unsigned short*)(ws + OFF_W2B);
  float2* ss1 = (float2*)(ws + OFF_SS1);
  float2* ssv = (float2*)(ws + OFF_SSV);
  for (int i = tid; i < CC*CC; i += stride) wkb[i] = f2b(ldmix(Wk, i, isbf));
  for (int i = tid; i < OGN*CC; i += stride) wvb[i] = f2b(ldmix(Wv, i, isbf));
  for (int i = tid; i < MIDM*CC; i += stride) {
    int m = i / CC, c = i % CC;
    w1ab[i] = f2b(ldmix(W1, (size_t)m*(2*CC) + c, isbf));
    w1bb[i] = f2b(ldmix(W1, (size_t)m*(2*CC) + CC + c, isbf));
  }
  for (int i = tid; i < OGN*MIDM; i += stride) {
    float w = ldmix(W2, i, isbf);
    ws[OFF_W2F + i] = w;
    w2b[i] = f2b(w);
  }
  for (int i = tid; i < CC; i += stride) {
    float s = ldmix(bn1_g, i, isbf) / sqrtf(ldmix(bn1_v, i, isbf) + 1e-5f);
    ss1[i] = make_float2(s, ldmix(bn1_b, i, isbf) - ldmix(bn1_m, i, isbf) * s);
  }
  for (int i = tid; i < MIDM; i += stride) {
    float s = ldmix(bn2_g, i, isbf) / sqrtf(ldmix(bn2_v, i, isbf) + 1e-5f);
    ws[OFF_SC2 + i] = s;
    ws[OFF_SH2 + i] = ldmix(bn2_b, i, isbf) - ldmix(bn2_m, i, isbf) * s;
    ws[OFF_B1F + i] = ldmix(b1, i, isbf);
  }
  for (int i = tid; i < OGN; i += stride) {
    float s = ldmix(bnv_g, i, isbf) / sqrtf(ldmix(bnv_v, i, isbf) + 1e-5f);
    ssv[i] = make_float2(s, ldmix(bnv_b, i, isbf) - ldmix(bnv_m, i, isbf) * s);
    ws[OFF_B2F + i] = ldmix(b2, i, isbf);
    ws[OFF_GNG + i] = ldmix(gn_g, i, isbf);
    ws[OFF_GNB + i] = ldmix(gn_b, i, isbf);
  }
  for (int i = tid; i < NB*MIDM; i += stride) ws[OFF_S1 + i] = 0.f;
  for (int i = tid; i < NB*MIDM*MIDM; i += stride) ws[OFF_GRAM + i] = 0.f;
}

// ---- x -> xt[b][pix][c] bf16, LDS-tiled transpose. grid (98,4) ----
__global__ __launch_bounds__(256) void k_tx(const void* __restrict__ x,
                                            float* __restrict__ ws) {
  __shared__ unsigned short tile[32*130];
  const bool isbf = ws[OFF_FLAG] > 0.5f;
  int b = blockIdx.y, pix0 = blockIdx.x * 32;
#pragma unroll
  for (int k = 0; k < 16; k++) {
    int idx = threadIdx.x + k*256;
    int c = idx >> 5, pl = idx & 31;
    tile[pl*130 + c] = f2b(ldmix(x, ((size_t)b*CC + c)*HWP + pix0 + pl, isbf));
  }
  __syncthreads();
  unsigned short* xt = (unsigned short*)(ws + OFF_XT);
#pragma unroll
  for (int k = 0; k < 16; k++) {
    int idx = threadIdx.x + k*256;
    int c = idx & 127, pl = idx >> 7;
    xt[((size_t)b*HWP + pix0 + pl)*CC + c] = tile[pl*130 + c];
  }
}

// ---- fused: ke = relu(bn1(Wk.x)) (kept in LDS), then
//      hq_t = W1a.x ; gk_t = W1b.ke. grid (49,1,4) ----
__global__ __launch_bounds__(256, 4) void k_keq(float* __restrict__ ws) {
  __shared__ unsigned short keL[4][16][136];   // [wave][pix][d], 16B-aligned rows
  int b = blockIdx.z;
  int w = threadIdx.x >> 6, lane = threadIdx.x & 63;
  int q = lane >> 4, l16 = lane & 15;
  int pix = blockIdx.x*64 + w*16 + l16;
  const unsigned short* xt = (const unsigned short*)(ws + OFF_XT) + ((size_t)b*HWP + pix)*CC;
  short8 Bx[4];
#pragma unroll
  for (int kk = 0; kk < 4; kk++) Bx[kk] = *(const short8*)(xt + kk*32 + q*8);
  const unsigned short* wkb = (const unsigned short*)(ws + OFF_WKB);
  const float2* ss = (const float2*)(ws + OFF_SS1);
  // phase 1: ke tile into LDS (C-layout: lane(q,l16) has d=ot*16+q*4+r, pixel=l16)
#pragma unroll
  for (int ot = 0; ot < 8; ot++) {
    int drow = ot*16 + l16;
    f32x4 c = {0.f, 0.f, 0.f, 0.f};
#pragma unroll
    for (int kk = 0; kk < 4; kk++)
      c = mfma16(*(const short8*)(wkb + (size_t)drow*CC + kk*32 + q*8), Bx[kk], c);
    int d0 = ot*16 + q*4;
    ushort4 st;
    { float2 s = ss[d0+0]; st.x = f2b(fmaxf(s.x*c[0] + s.y, 0.f)); }
    { float2 s = ss[d0+1]; st.y = f2b(fmaxf(s.x*c[1] + s.y, 0.f)); }
    { float2 s = ss[d0+2]; st.z = f2b(fmaxf(s.x*c[2] + s.y, 0.f)); }
    { float2 s = ss[d0+3]; st.w = f2b(fmaxf(s.x*c[3] + s.y, 0.f)); }
    *(ushort4*)&keL[w][l16][d0] = st;
  }
  __syncthreads();
  // phase 2: B-frags of ke from LDS; hq/gk MFMAs
  short8 Bk[4];
#pragma unroll
  for (int kk = 0; kk < 4; kk++) Bk[kk] = *(const short8*)&keL[w][l16][kk*32 + q*8];
  const unsigned short* w1a = (const unsigned short*)(ws + OFF_W1AB);
  const unsigned short* w1b = (const unsigned short*)(ws + OFF_W1BB);
  unsigned short* hqt = (unsigned short*)(ws + OFF_HQT) + ((size_t)b*HWP + pix)*MIDM;
  unsigned short* gkt = (unsigned short*)(ws + OFF_GKT) + ((size_t)b*HWP + pix)*MIDM;
#pragma unroll
  for (int mt = 0; mt < 2; mt++) {
    int mrow = mt*16 + l16;
    f32x4 ch = {0.f,0.f,0.f,0.f}, cg = {0.f,0.f,0.f,0.f};
#pragma unroll
    for (int kk = 0; kk < 4; kk++) {
      ch = mfma16(*(const short8*)(w1a + (size_t)mrow*CC + kk*32 + q*8), Bx[kk], ch);
      cg = mfma16(*(const short8*)(w1b + (size_t)mrow*CC + kk*32 + q*8), Bk[kk], cg);
    }
    int m0 = mt*16 + q*4;
    ushort4 sh, sg;
    sh.x = f2b(ch[0]); sh.y = f2b(ch[1]); sh.z = f2b(ch[2]); sh.w = f2b(ch[3]);
    sg.x = f2b(cg[0]); sg.y = f2b(cg[1]); sg.z = f2b(cg[2]); sg.w = f2b(cg[3]);
    *(ushort4*)(hqt + m0) = sh;
    *(ushort4*)(gkt + m0) = sg;
  }
}

// ---- v_t[pix][o] = bnv(Wv.x) via MFMA. grid (49,4,4) ----
__global__ __launch_bounds__(256, 4) void k_v(float* __restrict__ ws) {
  int b = blockIdx.z, by = blockIdx.y;
  int w = threadIdx.x >> 6, lane = threadIdx.x & 63;
  int q = lane >> 4, l16 = lane & 15;
  int pix = blockIdx.x*64 + w*16 + l16;
  const unsigned short* xt = (const unsigned short*)(ws + OFF_XT) + ((size_t)b*HWP + pix)*CC;
  short8 B[4];
#pragma unroll
  for (int kk = 0; kk < 4; kk++) B[kk] = *(const short8*)(xt + kk*32 + q*8);
  const unsigned short* wvb = (const unsigned short*)(ws + OFF_WVB);
  const float2* ss = (const float2*)(ws + OFF_SSV);
  unsigned short* vt = (unsigned short*)(ws + OFF_VT) + ((size_t)b*HWP + pix)*OGN;
#pragma unroll
  for (int ot = 0; ot < 8; ot++) {
    int orow = by*128 + ot*16 + l16;
    f32x4 c = {0.f, 0.f, 0.f, 0.f};
#pragma unroll
    for (int kk = 0; kk < 4; kk++)
      c = mfma16(*(const short8*)(wvb + (size_t)orow*CC + kk*32 + q*8), B[kk], c);
    int o0 = by*128 + ot*16 + q*4;
    ushort4 st;
    { float2 s = ss[o0+0]; st.x = f2b(s.x*c[0] + s.y); }
    { float2 s = ss[o0+1]; st.y = f2b(s.x*c[1] + s.y); }
    { float2 s = ss[o0+2]; st.z = f2b(s.x*c[2] + s.y); }
    { float2 s = ss[o0+3]; st.w = f2b(s.x*c[3] + s.y); }
    *(ushort4*)(vt + o0) = st;
  }
}

// ---- hs[b][p][pix][m] = relu(bn2(hq + shift(gk) + b1)) bf16. grid (13,9,4) ----
__global__ __launch_bounds__(256) void k_h(float* __restrict__ ws) {
  int b = blockIdx.z, p = blockIdx.y;
  int pix = blockIdx.x*256 + threadIdx.x;
  if (pix >= HWP) return;
  int h0 = pix / WD, w0 = pix - h0*WD;
  int nh = h0 + p/3 - 1, nw = w0 + p%3 - 1;
  bool valid = ((unsigned)nh < (unsigned)WD) && ((unsigned)nw < (unsigned)WD);
  int npix = nh*WD + nw;
  const unsigned short* hq = (const unsigned short*)(ws + OFF_HQT) + ((size_t)b*HWP + pix)*MIDM;
  const unsigned short* gk = (const unsigned short*)(ws + OFF_GKT) + ((size_t)b*HWP + npix)*MIDM;
  unsigned short* hd = (unsigned short*)(ws + OFF_HS) + ((size_t)((b*9 + p))*HWP + pix)*MIDM;
  float hv[MIDM];
#pragma unroll
  for (int k = 0; k < 4; k++) {
    short8 t = *(const short8*)(hq + k*8);
#pragma unroll
    for (int j = 0; j < 8; j++) hv[k*8+j] = b2f((unsigned short)t[j]);
  }
  if (valid) {
#pragma unroll
    for (int k = 0; k < 4; k++) {
      short8 t = *(const short8*)(gk + k*8);
#pragma unroll
      for (int j = 0; j < 8; j++) hv[k*8+j] += b2f((unsigned short)t[j]);
    }
  }
#pragma unroll
  for (int k = 0; k < 8; k++) {
    ushort4 st;
    int m = k*4;
    st.x = f2b(fmaxf(ws[OFF_SC2+m+0]*(hv[m+0] + ws[OFF_B1F+m+0]) + ws[OFF_SH2+m+0], 0.f));
    st.y = f2b(fmaxf(ws[OFF_SC2+m+1]*(hv[m+1] + ws[OFF_B1F+m+1]) + ws[OFF_SH2+m+1], 0.f));
    st.z = f2b(fmaxf(ws[OFF_SC2+m+2]*(hv[m+2] + ws[OFF_B1F+m+2]) + ws[OFF_SH2+m+2], 0.f));
    st.w = f2b(fmaxf(ws[OFF_SC2+m+3]*(hv[m+3] + ws[OFF_B1F+m+3]) + ws[OFF_SH2+m+3], 0.f));
    *(ushort4*)(hd + m) = st;
  }
}

// ---- Gram + S1 via MFMA. grid (49,4) ----
__global__ __launch_bounds__(256) void k_gram(float* __restrict__ ws) {
  int b = blockIdx.y;
  int w = threadIdx.x >> 6, lane = threadIdx.x & 63;
  int q = lane >> 4, l16 = lane & 15;
  int g = blockIdx.x*4 + w;   // 0..195
  const unsigned short* hsb = (const unsigned short*)(ws + OFF_HS) + (size_t)b*9*HWP*MIDM;
  f32x4 gLL = {0,0,0,0}, gLH = {0,0,0,0}, gHL = {0,0,0,0}, gHH = {0,0,0,0};
  f32x4 sL = {0,0,0,0}, sH = {0,0,0,0};
  short8 ones;
#pragma unroll
  for (int j = 0; j < 8; j++) ones[j] = (short)0x3F80;
  for (int ci = g; ci < 882; ci += 196) {
    int p = ci / 98, ch = ci - p*98;
    int pix0 = ch*32;
    const unsigned short* base = hsb + ((size_t)p*HWP + pix0)*MIDM;
    short8 alo, ahi;
#pragma unroll
    for (int j = 0; j < 8; j++) {
      const unsigned short* row = base + (q*8 + j)*MIDM;
      alo[j] = (short)row[l16];
      ahi[j] = (short)row[l16 + 16];
    }
    gLL = mfma16(alo, alo, gLL);
    gLH = mfma16(alo, ahi, gLH);
    gHL = mfma16(ahi, alo, gHL);
    gHH = mfma16(ahi, ahi, gHH);
    sL = mfma16(alo, ones, sL);
    sH = mfma16(ahi, ones, sH);
  }
  float* G = ws + OFF_GRAM + b*MIDM*MIDM;
#pragma unroll
  for (int r = 0; r < 4; r++) {
    atomicAdd(&G[(q*4 + r)*MIDM + l16],           gLL[r]);
    atomicAdd(&G[(q*4 + r)*MIDM + 16 + l16],      gLH[r]);
    atomicAdd(&G[(16 + q*4 + r)*MIDM + l16],      gHL[r]);
    atomicAdd(&G[(16 + q*4 + r)*MIDM + 16 + l16], gHH[r]);
  }
  if (l16 == 0) {
#pragma unroll
    for (int r = 0; r < 4; r++) {
      atomicAdd(&ws[OFF_S1 + b*MIDM + q*4 + r],      sL[r]);
      atomicAdd(&ws[OFF_S1 + b*MIDM + 16 + q*4 + r], sH[r]);
    }
  }
}

// ---- GN stats -> PQ float2 per (b,o). grid (4) x 512 ----
__global__ __launch_bounds__(512) void k_stats(float* __restrict__ ws) {
  __shared__ float Gs[MIDM*MIDM], S1s[MIDM], saS[OGN], sqS[OGN], muS[128], invS[128];
  int b = blockIdx.x, o = threadIdx.x;
  Gs[o] = ws[OFF_GRAM + b*MIDM*MIDM + o];
  Gs[512 + o] = ws[OFF_GRAM + b*MIDM*MIDM + 512 + o];
  if (o < MIDM) S1s[o] = ws[OFF_S1 + b*MIDM + o];
  __syncthreads();
  float w2[MIDM];
#pragma unroll
  for (int m = 0; m < MIDM; m++) w2[m] = ws[OFF_W2F + o*MIDM + m];
  float dotS = 0.f;
#pragma unroll
  for (int m = 0; m < MIDM; m++) dotS += w2[m] * S1s[m];
  float quad = 0.f;
  for (int a = 0; a < MIDM; a++) {
    float t = 0.f;
#pragma unroll
    for (int c = 0; c < MIDM; c++) t += Gs[a*MIDM + c] * w2[c];
    quad += w2[a] * t;
  }
  float b2o = ws[OFF_B2F + o];
  const float M = 9.f * HWP;
  saS[o] = dotS + b2o * M;
  sqS[o] = quad + 2.f*b2o*dotS + b2o*b2o*M;
  __syncthreads();
  if (o < 128) {
    float sa = saS[4*o] + saS[4*o+1] + saS[4*o+2] + saS[4*o+3];
    float sq = sqS[4*o] + sqS[4*o+1] + sqS[4*o+2] + sqS[4*o+3];
    const float invN = 1.f / (4.f * M);
    float mu = sa * invN;
    float var = sq * invN - mu*mu;
    muS[o] = mu;
    invS[o] = 1.f / sqrtf(var + 1e-5f);
  }
  __syncthreads();
  int co = o >> 2;
  float alpha = ws[OFF_GNG + o] * invS[co];
  ((float2*)(ws + OFF_PQ))[b*OGN + o] =
      make_float2(alpha, alpha*b2o + ws[OFF_GNB + o] - muS[co]*alpha);
}

// ---- vt <- P*vt (in place); w[b][pix][co] = sum_gc Q*v. grid (784) ----
__global__ __launch_bounds__(256) void k_vpq(float* __restrict__ ws) {
  int t = blockIdx.x*256 + threadIdx.x;
  int pixg = t >> 4;
  int b = pixg / HWP, pix = pixg - b*HWP;
  int oc = (t & 15) * 32;
  unsigned short* vt = (unsigned short*)(ws + OFF_VT) + ((size_t)b*HWP + pix)*OGN + oc;
  const float2* pq = (const float2*)(ws + OFF_PQ) + b*OGN + oc;
  unsigned short* wq = (unsigned short*)(ws + OFF_WQ) + ((size_t)b*HWP + pix)*CC + (oc >> 2);
  float wacc[8];
#pragma unroll
  for (int j = 0; j < 8; j++) wacc[j] = 0.f;
#pragma unroll
  for (int ch = 0; ch < 4; ch++) {
    short8 vv = *(short8*)(vt + ch*8);
#pragma unroll
    for (int j = 0; j < 8; j++) {
      int oo = ch*8 + j;
      float v = b2f((unsigned short)vv[j]);
      float2 P = pq[oo];
      wacc[oo >> 2] += P.y * v;
      vv[j] = (short)f2b(P.x * v);
    }
    *(short8*)(vt + ch*8) = vv;
  }
  short8 st;
#pragma unroll
  for (int j = 0; j < 8; j++) st[j] = (short)f2b(wacc[j]);
  *(short8*)wq = st;
}

// ---- wsum[b][pix][co] = 3x3 box sum of w. grid (196) ----
__global__ __launch_bounds__(256) void k_wbox(float* __restrict__ ws) {
  int t = blockIdx.x*256 + threadIdx.x;
  int pixg = t >> 2;
  int b = pixg / HWP, pix = pixg - b*HWP;
  int c0 = (t & 3) * 32;
  int h0 = pix / WD, w0 = pix - h0*WD;
  const unsigned short* wq = (const unsigned short*)(ws + OFF_WQ) + (size_t)b*HWP*CC + c0;
  float acc[32];
#pragma unroll
  for (int j = 0; j < 32; j++) acc[j] = 0.f;
  for (int p = 0; p < 9; p++) {
    int nh = h0 + p/3 - 1, nw = w0 + p%3 - 1;
    if ((unsigned)nh >= (unsigned)WD || (unsigned)nw >= (unsigned)WD) continue;
    const unsigned short* row = wq + (size_t)(nh*WD + nw)*CC;
#pragma unroll
    for (int ch = 0; ch < 4; ch++) {
      short8 vv = *(const short8*)(row + ch*8);
#pragma unroll
      for (int j = 0; j < 8; j++) acc[ch*8+j] += b2f((unsigned short)vv[j]);
    }
  }
  unsigned short* dst = (unsigned short*)(ws + OFF_WSUM) + ((size_t)b*HWP + pix)*CC + c0;
#pragma unroll
  for (int ch = 0; ch < 4; ch++) {
    short8 st;
#pragma unroll
    for (int j = 0; j < 8; j++) st[j] = (short)f2b(acc[ch*8+j]);
    *(short8*)(dst + ch*8) = st;
  }
}

// ---- epilogue: out[b,co,pix] = wsum + sum_p sum_o (W2.h)*(P*v). grid (49,4,4) ----
__global__ __launch_bounds__(256, 4) void k_out(const float* __restrict__ ws,
                                                void* __restrict__ outp) {
  int b = blockIdx.z, by = blockIdx.y;
  int w = threadIdx.x >> 6, lane = threadIdx.x & 63;
  int q = lane >> 4, l16 = lane & 15;
  int pix = blockIdx.x*64 + w*16 + l16;
  int h0 = pix / WD, w0 = pix - h0*WD;
  const bool isbf = ws[OFF_FLAG] > 0.5f;
  const unsigned short* w2b = (const unsigned short*)(ws + OFF_W2B);
  short8 A[8];
#pragma unroll
  for (int ot = 0; ot < 8; ot++) {
    int orow = by*128 + ot*16 + l16;
    A[ot] = *(const short8*)(w2b + (size_t)orow*MIDM + q*8);
  }
  const unsigned short* vt = (const unsigned short*)(ws + OFF_VT) + (size_t)b*HWP*OGN;
  const unsigned short* hsb = (const unsigned short*)(ws + OFF_HS) + (size_t)b*9*HWP*MIDM;
  const unsigned short* wsum = (const unsigned short*)(ws + OFF_WSUM) + ((size_t)b*HWP + pix)*CC;
  float acc[8];
#pragma unroll
  for (int ot = 0; ot < 8; ot++) acc[ot] = b2f(wsum[by*32 + ot*4 + q]);
  for (int p = 0; p < 9; p++) {
    int nh = h0 + p/3 - 1, nw = w0 + p%3 - 1;
    bool valid = ((unsigned)nh < (unsigned)WD) && ((unsigned)nw < (unsigned)WD);
    int npix = valid ? (nh*WD + nw) : 0;
    short8 B = *(const short8*)(hsb + ((size_t)p*HWP + pix)*MIDM + q*8);
#pragma unroll
    for (int ot = 0; ot < 8; ot++) {
      f32x4 c = {0.f, 0.f, 0.f, 0.f};
      c = mfma16(A[ot], B, c);
      int o0 = by*128 + ot*16 + q*4;
      if (valid) {
        ushort4 vv = *(const ushort4*)(vt + (size_t)npix*OGN + o0);
        acc[ot] += c[0]*b2f(vv.x) + c[1]*b2f(vv.y) + c[2]*b2f(vv.z) + c[3]*b2f(vv.w);
      }
    }
  }
#pragma unroll
  for (int ot = 0; ot < 8; ot++) {
    int co = by*32 + ot*4 + q;
    size_t oidx = ((size_t)b*128 + co)*HWP + pix;
    if (isbf) ((unsigned short*)outp)[oidx] = f2b(acc[ot]);
    else      ((float*)outp)[oidx] = acc[ot];
  }
}

extern "C" void kernel_launch(void* const* d_in, const int* in_sizes, int n_in,
                              void* d_out, int out_size, void* d_ws, size_t ws_size,
                              hipStream_t stream) {
  float* ws = (float*)d_ws;
  hipLaunchKernelGGL(k_detect, dim3(1), dim3(256), 0, stream,
                     (const unsigned short*)d_in[0], ws);
  hipLaunchKernelGGL(k_prep, dim3(64), dim3(256), 0, stream,
                     d_in[1], d_in[2], d_in[3], d_in[4], d_in[5],
                     d_in[6], d_in[7], d_in[8], d_in[9], d_in[10], d_in[11],
                     d_in[12], d_in[13], d_in[14], d_in[15], d_in[16],
                     d_in[17], d_in[18], d_in[19], d_in[20], ws);
  hipLaunchKernelGGL(k_tx,   dim3(98, 4),     dim3(256), 0, stream, d_in[0], ws);
  hipLaunchKernelGGL(k_keq,  dim3(49, 1, 4),  dim3(256), 0, stream, ws);
  hipLaunchKernelGGL(k_v,    dim3(49, 4, 4),  dim3(256), 0, stream, ws);
  hipLaunchKernelGGL(k_h,    dim3(13, 9, 4),  dim3(256), 0, stream, ws);
  hipLaunchKernelGGL(k_gram, dim3(49, 4),     dim3(256), 0, stream, ws);
  hipLaunchKernelGGL(k_stats,dim3(4),         dim3(512), 0, stream, ws);
  hipLaunchKernelGGL(k_vpq,  dim3(784),       dim3(256), 0, stream, ws);
  hipLaunchKernelGGL(k_wbox, dim3(196),       dim3(256), 0, stream, ws);
  hipLaunchKernelGGL(k_out,  dim3(49, 4, 4),  dim3(256), 0, stream, ws, d_out);
}